// Round 10
// baseline (160.965 us; speedup 1.0000x reference)
//
#include <hip/hip_runtime.h>

#define DIN 512
#define DOUT 512

typedef int v4i __attribute__((ext_vector_type(4)));
typedef float v4f __attribute__((ext_vector_type(4)));

#define WAITLGKM0() asm volatile("s_waitcnt lgkmcnt(0)" ::: "memory")

// exact-divide quantize (weights/bias path, matches ref bit-for-bit)
__device__ __forceinline__ int q8f(float v, float s) {
    int i = (int)rintf(v / s);
    i = i < -128 ? -128 : (i > 127 ? 127 : i);
    return i & 255;
}
// multiply-by-reciprocal quantize (activation path; flip prob ~2^-22, contribution ~0.005 << 0.0525)
__device__ __forceinline__ int q8m(float v, float inv) {
    int i = (int)rintf(v * inv);
    i = i < -128 ? -128 : (i > 127 ? 127 : i);
    return i & 255;
}

// ---------------- Kernel 1: global absmax of x ----------------
__global__ void absmax_kernel(const float4* __restrict__ x4, unsigned* __restrict__ amax, int n4) {
    float m = 0.f;
    int stride = gridDim.x * blockDim.x;
    for (int i = blockIdx.x * blockDim.x + threadIdx.x; i < n4; i += stride) {
        float4 v = x4[i];
        m = fmaxf(m, fmaxf(fmaxf(fabsf(v.x), fabsf(v.y)), fmaxf(fabsf(v.z), fabsf(v.w))));
    }
#pragma unroll
    for (int off = 32; off; off >>= 1) m = fmaxf(m, __shfl_xor(m, off));
    __shared__ float sm[4];
    int lane = threadIdx.x & 63, w = threadIdx.x >> 6;
    if (lane == 0) sm[w] = m;
    __syncthreads();
    if (threadIdx.x == 0) {
        m = fmaxf(fmaxf(sm[0], sm[1]), fmaxf(sm[2], sm[3]));
        atomicMax(amax, __float_as_uint(m));  // positive floats: uint compare == float compare
    }
}

// ---------------- Kernel 2: per-row weight quant ----------------
__global__ void quantw_kernel(const float* __restrict__ w,
                              char* __restrict__ wq, float* __restrict__ wsc) {
    int gid = blockIdx.x * blockDim.x + threadIdx.x;
    int row = gid >> 6, lane = gid & 63;
    const float4* r4 = (const float4*)(w + (long)row * DIN);
    float4 a = r4[lane * 2];
    float4 b = r4[lane * 2 + 1];
    float m = fmaxf(fmaxf(fmaxf(fabsf(a.x), fabsf(a.y)), fabsf(a.z)),
                    fmaxf(fmaxf(fabsf(a.w), fabsf(b.x)),
                          fmaxf(fmaxf(fabsf(b.y), fabsf(b.z)), fabsf(b.w))));
#pragma unroll
    for (int off = 32; off; off >>= 1) m = fmaxf(m, __shfl_xor(m, off));
    float s = m / 127.0f;
    int lo = q8f(a.x, s) | (q8f(a.y, s) << 8) | (q8f(a.z, s) << 16) | (q8f(a.w, s) << 24);
    int hi = q8f(b.x, s) | (q8f(b.y, s) << 8) | (q8f(b.z, s) << 16) | (q8f(b.w, s) << 24);
    ((int2*)(wq + (long)row * DIN))[lane] = make_int2(lo, hi);
    if (lane == 0) wsc[row] = s;
}

// ---------------- Kernel 2b: combined scales + quantized bias ----------------
__global__ void quantb_kernel(const float* __restrict__ bias, const float* __restrict__ wsc,
                              const unsigned* __restrict__ amax,
                              float* __restrict__ bs, float* __restrict__ bq) {
    int oc = threadIdx.x;
    float as = __uint_as_float(*amax) / 127.0f;
    float s = as * wsc[oc];
    bs[oc] = s;
    bq[oc] = rintf(bias[oc] / s) * s;
}

// ---------------- Kernel 3: persistent w-in-registers GEMM ----------------
// 256 blocks (1/CU) x 512 thr (8 waves). Wave wid owns oc [wid*64, +64): its
// 32 KB of wq lives in 128 VGPRs (32 A-frags), loaded ONCE from L2.
// Block loops 4 m-tiles of 64 rows x 512 k:
//   - x fp32 loaded flat-coalesced (8KB/instr/wave), quantized, written to a
//     row-major [64][512] int8 LDS tile, XOR-swizzled (^(row&7)<<4): quant
//     writes and b128 frag reads are both ~2-way (free, m136).
//   - k-loop: 32 ds_read_b128 + 128 MFMA per wave. NO barriers, NO global
//     loads, NO waitcnt inside.
//   - next tile's x issued in 4-float4 batches >=1500cy before consumption.
//   - epilogue: R8's validated LDS-transposed full-line nt-store (1KB/instr).
// Only per-tile syncs remain (~6 barriers / ~5000cy tile).
__global__ __launch_bounds__(512, 2) void gemm_kernel(
    const float* __restrict__ x, const char* __restrict__ wq,
    const float* __restrict__ bs, const float* __restrict__ bq,
    const unsigned* __restrict__ amax, float* __restrict__ out) {
    __shared__ char xb[2][32768];    // x int8 dbuf, [64][512] swizzled
    __shared__ char ostage[65536];   // [32][2048B] f32 out-stage, swizzled
    const int t = threadIdx.x, lane = t & 63, wid = t >> 6;
    const float inv_as = 1.0f / (__uint_as_float(*amax) / 127.0f);

    // ---- w fragments -> registers (frag(ks,no): 16 oc x 64 k, lane: oc=l&15, kq=l>>4)
    v4i wf[8][4];
    {
        const char* wg = wq + (wid * 64 + (lane & 15)) * DIN + (lane >> 4) * 16;
#pragma unroll
        for (int ks = 0; ks < 8; ks++)
#pragma unroll
            for (int no = 0; no < 4; no++)
                wf[ks][no] = *(const v4i*)(wg + no * 16 * DIN + ks * 64);
    }

    const float4* x4 = (const float4*)x;
    float4 xv[8];

// flat float4 index within tile-half HH: f = HH*4096 + i*512 + t (rows 32HH..+32)
#define LOADQ(J, HH, I0) { _Pragma("unroll") for (int i = (I0); i < (I0) + 4; i++) \
        xv[i] = x4[((long)blockIdx.x * 4 + (J)) * 8192 + (HH) * 4096 + i * 512 + t]; }
#define QUANTH(BUF, HH) { _Pragma("unroll") for (int i = 0; i < 8; i++) { \
        int f = (HH) * 4096 + i * 512 + t; int row = f >> 7, c4 = f & 127; \
        int q = q8m(xv[i].x, inv_as) | (q8m(xv[i].y, inv_as) << 8) | \
                (q8m(xv[i].z, inv_as) << 16) | (q8m(xv[i].w, inv_as) << 24); \
        *(int*)&(BUF)[(row * 512 + c4 * 4) ^ ((row & 7) << 4)] = q; } }
#define KLOOP4(BUF, KS0) { _Pragma("unroll") for (int ks = (KS0); ks < (KS0) + 4; ks++) { \
        v4i xf[4]; \
        _Pragma("unroll") for (int mi = 0; mi < 4; mi++) { \
            int m_ = mi * 16 + (lane & 15); \
            xf[mi] = *(const v4i*)&(BUF)[(m_ * 512 + ks * 64 + (lane >> 4) * 16) ^ ((m_ & 7) << 4)]; } \
        _Pragma("unroll") for (int no = 0; no < 4; no++) \
            _Pragma("unroll") for (int mi = 0; mi < 4; mi++) \
                acc[mi][no] = __builtin_amdgcn_mfma_i32_16x16x64_i8(wf[ks][no], xf[mi], acc[mi][no], 0, 0, 0); } }
// D layout: row=(l>>4)*4+r = oc-local (4 consecutive oc), col=l&15 = m-local.
#define EPI(H, M0) { \
    _Pragma("unroll") for (int no = 0; no < 4; no++) { \
        int oc0 = wid * 64 + no * 16 + (lane >> 4) * 4; \
        float4 s4 = *(const float4*)(bs + oc0); \
        float4 q4 = *(const float4*)(bq + oc0); \
        _Pragma("unroll") for (int mm = 0; mm < 2; mm++) { \
            int mloc = mm * 16 + (lane & 15); \
            v4f v; \
            v[0] = (float)acc[2 * (H) + mm][no][0] * s4.x + q4.x; \
            v[1] = (float)acc[2 * (H) + mm][no][1] * s4.y + q4.y; \
            v[2] = (float)acc[2 * (H) + mm][no][2] * s4.z + q4.z; \
            v[3] = (float)acc[2 * (H) + mm][no][3] * s4.w + q4.w; \
            *(v4f*)&ostage[(mloc * 2048 + oc0 * 4) ^ ((mloc & 15) << 4)] = v; } } \
    WAITLGKM0(); \
    __builtin_amdgcn_s_barrier(); \
    { const char* ob = (const char*)out + ((M0) + (H) * 32) * 2048 + t * 16; \
      _Pragma("unroll") for (int i = 0; i < 8; i++) { \
        int linear = t * 16 + i * 8192; int r = linear >> 11; \
        v4f v = *(const v4f*)&ostage[linear ^ ((r & 15) << 4)]; \
        __builtin_nontemporal_store(v, (v4f*)(ob + i * 8192)); } } \
    __builtin_amdgcn_s_barrier(); }

    // ---- prologue: stage tile 0
    LOADQ(0, 0, 0) LOADQ(0, 0, 4)
    QUANTH(xb[0], 0)
    LOADQ(0, 1, 0) LOADQ(0, 1, 4)
    QUANTH(xb[0], 1)
    WAITLGKM0();
    __builtin_amdgcn_s_barrier();

    for (int j = 0; j < 4; j++) {
        const long m0 = ((long)blockIdx.x * 4 + j) * 64;
        char* cur = xb[j & 1];
        char* nxt = xb[(j & 1) ^ 1];
        v4i acc[4][4] = {};

        if (j < 3) { LOADQ(j + 1, 0, 0) }          // next-tile h0 batch A in flight
        asm volatile("" ::: "memory");
        KLOOP4(cur, 0)
        if (j < 3) { LOADQ(j + 1, 0, 4) }          // h0 batch B, ~1500cy before use
        asm volatile("" ::: "memory");
        KLOOP4(cur, 4)
        if (j < 3) { QUANTH(nxt, 0) LOADQ(j + 1, 1, 0) }
        EPI(0, m0)
        if (j < 3) { LOADQ(j + 1, 1, 4) }
        EPI(1, m0)
        if (j < 3) { QUANTH(nxt, 1) }
        WAITLGKM0();
        __builtin_amdgcn_s_barrier();              // nxt complete; ostage reads done
    }
#undef LOADQ
#undef QUANTH
#undef KLOOP4
#undef EPI
}

extern "C" void kernel_launch(void* const* d_in, const int* in_sizes, int n_in,
                              void* d_out, int out_size, void* d_ws, size_t ws_size,
                              hipStream_t stream) {
    const float* x    = (const float*)d_in[0];
    const float* w    = (const float*)d_in[1];
    const float* bias = (const float*)d_in[2];
    float* out = (float*)d_out;

    char* ws = (char*)d_ws;
    unsigned* amax = (unsigned*)ws;
    char* wq   = ws + 64;
    float* wsc = (float*)(ws + 64 + (long)DOUT * DIN);
    float* bs  = wsc + DOUT;
    float* bq  = bs + DOUT;

    hipMemsetAsync(d_ws, 0, 64, stream);
    quantw_kernel<<<(DOUT * 64) / 256, 256, 0, stream>>>(w, wq, wsc);
    absmax_kernel<<<2048, 256, 0, stream>>>((const float4*)x, amax, in_sizes[0] / 4);
    quantb_kernel<<<1, DOUT, 0, stream>>>(bias, wsc, amax, bs, bq);
    gemm_kernel<<<256, 512, 0, stream>>>(x, wq, bs, bq, amax, out);
}

// Round 11
// 120.820 us; speedup vs baseline: 1.3323x; 1.3323x over previous
//
#include <hip/hip_runtime.h>

#define DIN 512
#define DOUT 512
#define BM 64

typedef int v4i __attribute__((ext_vector_type(4)));
typedef float v4f __attribute__((ext_vector_type(4)));

#define WAITVM(n) asm volatile("s_waitcnt vmcnt(" #n ")" ::: "memory")
#define WAITLGKM0() asm volatile("s_waitcnt lgkmcnt(0)" ::: "memory")

// exact-divide quantize (weights/bias path, matches ref bit-for-bit)
__device__ __forceinline__ int q8f(float v, float s) {
    int i = (int)rintf(v / s);
    i = i < -128 ? -128 : (i > 127 ? 127 : i);
    return i & 255;
}
// multiply-by-reciprocal quantize (activation path; flip prob ~2^-22)
__device__ __forceinline__ int q8m(float v, float inv) {
    int i = (int)rintf(v * inv);
    i = i < -128 ? -128 : (i > 127 ? 127 : i);
    return i & 255;
}

// ---------------- Kernel 1: global absmax of x ----------------
__global__ void absmax_kernel(const float4* __restrict__ x4, unsigned* __restrict__ amax, int n4) {
    float m = 0.f;
    int stride = gridDim.x * blockDim.x;
    for (int i = blockIdx.x * blockDim.x + threadIdx.x; i < n4; i += stride) {
        float4 v = x4[i];
        m = fmaxf(m, fmaxf(fmaxf(fabsf(v.x), fabsf(v.y)), fmaxf(fabsf(v.z), fabsf(v.w))));
    }
#pragma unroll
    for (int off = 32; off; off >>= 1) m = fmaxf(m, __shfl_xor(m, off));
    __shared__ float sm[4];
    int lane = threadIdx.x & 63, w = threadIdx.x >> 6;
    if (lane == 0) sm[w] = m;
    __syncthreads();
    if (threadIdx.x == 0) {
        m = fmaxf(fmaxf(sm[0], sm[1]), fmaxf(sm[2], sm[3]));
        atomicMax(amax, __float_as_uint(m));  // positive floats: uint compare == float compare
    }
}

// ---------------- Kernel 2: per-row weight quant (+ amax zero-init) ----------------
__global__ void quantw_kernel(const float* __restrict__ w,
                              char* __restrict__ wq, float* __restrict__ wsc,
                              unsigned* __restrict__ amax) {
    int gid = blockIdx.x * blockDim.x + threadIdx.x;
    if (gid == 0) *amax = 0u;   // quantw completes before absmax launches (same stream)
    int row = gid >> 6, lane = gid & 63;
    const float4* r4 = (const float4*)(w + (long)row * DIN);
    float4 a = r4[lane * 2];
    float4 b = r4[lane * 2 + 1];
    float m = fmaxf(fmaxf(fmaxf(fabsf(a.x), fabsf(a.y)), fabsf(a.z)),
                    fmaxf(fmaxf(fabsf(a.w), fabsf(b.x)),
                          fmaxf(fmaxf(fabsf(b.y), fabsf(b.z)), fabsf(b.w))));
#pragma unroll
    for (int off = 32; off; off >>= 1) m = fmaxf(m, __shfl_xor(m, off));
    float s = m / 127.0f;
    int lo = q8f(a.x, s) | (q8f(a.y, s) << 8) | (q8f(a.z, s) << 16) | (q8f(a.w, s) << 24);
    int hi = q8f(b.x, s) | (q8f(b.y, s) << 8) | (q8f(b.z, s) << 16) | (q8f(b.w, s) << 24);
    ((int2*)(wq + (long)row * DIN))[lane] = make_int2(lo, hi);
    if (lane == 0) wsc[row] = s;
}

// ---------------- Kernel 2b: combined scales + quantized bias (fallback path only) ----------------
__global__ void quantb_kernel(const float* __restrict__ bias, const float* __restrict__ wsc,
                              const unsigned* __restrict__ amax,
                              float* __restrict__ bs, float* __restrict__ bq) {
    int oc = threadIdx.x;
    float as = __uint_as_float(*amax) / 127.0f;
    float s = as * wsc[oc];
    bs[oc] = s;
    bq[oc] = rintf(bias[oc] / s) * s;
}

// ---------------- Kernel 2c: quantize x -> chunk-linear int8 (v2: line-per-thread) ----------------
// x8 byte(T,ks,c,kq,r) = T*32768 + ks*4096 + c*1024 + kq*256 + r*16  (validated R9 layout).
// Thread g owns line g: reads 16 consecutive fp32 (64B) of row T*64+c*16+r at col ks*64+kq*16,
// writes ONE 16B line at x8 + g*16 -> wave writes are perfectly lane-linear 1KB/instr.
__global__ __launch_bounds__(512) void quantx_kernel(
    const float* __restrict__ x, const unsigned* __restrict__ amax,
    char* __restrict__ x8) {
    const long g = (long)blockIdx.x * 512 + threadIdx.x;
    const float inv_as = 1.0f / (__uint_as_float(*amax) / 127.0f);
    const long T = g >> 11;
    const int L = (int)(g & 2047);
    const int ks = L >> 8, c = (L >> 6) & 3, kq = (L >> 4) & 3, r = L & 15;
    const float4* src = (const float4*)(x + (T * 64 + c * 16 + r) * DIN + ks * 64 + kq * 16);
    float4 v0 = src[0], v1 = src[1], v2 = src[2], v3 = src[3];
    v4i q;
    q[0] = q8m(v0.x, inv_as) | (q8m(v0.y, inv_as) << 8) | (q8m(v0.z, inv_as) << 16) | (q8m(v0.w, inv_as) << 24);
    q[1] = q8m(v1.x, inv_as) | (q8m(v1.y, inv_as) << 8) | (q8m(v1.z, inv_as) << 16) | (q8m(v1.w, inv_as) << 24);
    q[2] = q8m(v2.x, inv_as) | (q8m(v2.y, inv_as) << 8) | (q8m(v2.z, inv_as) << 16) | (q8m(v2.w, inv_as) << 24);
    q[3] = q8m(v3.x, inv_as) | (q8m(v3.y, inv_as) << 8) | (q8m(v3.z, inv_as) << 16) | (q8m(v3.w, inv_as) << 24);
    *(v4i*)(x8 + g * 16) = q;
}

// ---------------- Kernel 3: pure-int8 GEMM, register-x, counted-vmcnt dbuf ----------------
// BM=64 x BN=512, 512 thr / 8 waves (2m x 4oc), wave tile 32m x 128oc (acc 64 VGPR).
// x-frags: global->VGPR, xa[3] rotation, issued 2 STEPS (>=1500cy) before use
// (fixes R9's 1-step stall). w: LDS dbuf via global_load_lds (L2-resident),
// R8's proven 2-barrier STEP; hand-traced ladder vmcnt(6,8,8,8,8,8,6,0).
// K-loop: zero VALU, zero fp32. quantb folded into prologue (bsl/bql in LDS).
// Epilogue: R8's LDS-transposed full-line nt stores.
__global__ __launch_bounds__(512, 4) void gemm_kernel(
    const char* __restrict__ x8, const char* __restrict__ wq,
    const float* __restrict__ wsc, const float* __restrict__ bias,
    const unsigned* __restrict__ amax, float* __restrict__ out) {
    __shared__ char wl[2][32768];             // dbuf w; reused as 64KB f32 out-stage
    __shared__ __align__(16) float bsl[512];  // combined scale per oc
    __shared__ __align__(16) float bql[512];  // quantized bias per oc
    const int t = threadIdx.x, lane = t & 63, wid = t >> 6;
    const int wm = wid >> 2, wn = wid & 3;
    const long rbase = (long)blockIdx.x * BM;
    const char* wgsrc = wq + ((wid * 64) + (lane & 15)) * DIN + (lane >> 4) * 16;
    const char* xtile = x8 + (long)blockIdx.x * 32768 + wm * 2048 + lane * 16;

    v4i xa[3][2];
    v4i acc[2][8] = {};

    // fold quantb: one oc per thread
    {
        float as = __uint_as_float(*amax) / 127.0f;
        float s = as * wsc[t];
        bsl[t] = s;
        bql[t] = rintf(bias[t] / s) * s;
    }

#define DMAW(n, b) { _Pragma("unroll") for (int jj = 0; jj < 4; jj++) \
    __builtin_amdgcn_global_load_lds( \
        (const __attribute__((address_space(1))) unsigned*)(wgsrc + jj * 16 * DIN + (n) * 64), \
        (__attribute__((address_space(3))) unsigned*)(wl[b] + (wid * 4 + jj) * 1024), 16, 0, 0); }
#define LDXR(n) { xa[(n) % 3][0] = *(const v4i*)(xtile + (n) * 4096); \
                  xa[(n) % 3][1] = *(const v4i*)(xtile + (n) * 4096 + 1024); }
#define COMPUTE(KS) { _Pragma("unroll") for (int ni = 0; ni < 8; ni++) { \
    v4i wb = *(const v4i*)&wl[(KS) & 1][(wn * 8 + ni) * 1024 + lane * 16]; \
    acc[0][ni] = __builtin_amdgcn_mfma_i32_16x16x64_i8(wb, xa[(KS) % 3][0], acc[0][ni], 0, 0, 0); \
    acc[1][ni] = __builtin_amdgcn_mfma_i32_16x16x64_i8(wb, xa[(KS) % 3][1], acc[1][ni], 0, 0, 0); } }
// STEP(KS): entering queue (steady) = [x(KS):2, w(KS):4, x(KS+1):2, w(KS+1):4].
// Issue x(KS+2), drain to VM (x(KS)+w(KS) retired, never to 0 mid-loop), barrier
// (w(KS) visible), compute, barrier (all waves done reading wl[KS&1]), then
// DMA w(KS+2) into the freed buffer.
#define STEP(KS, VM) { \
    if ((KS) + 2 < 8) LDXR((KS) + 2); \
    WAITVM(VM); \
    __builtin_amdgcn_s_barrier(); \
    COMPUTE(KS); \
    __builtin_amdgcn_s_barrier(); \
    if ((KS) + 2 < 8) DMAW((KS) + 2, (KS) & 1); }

    // prologue: queue = [x0:2, x1:2, w0:4, w1:4]
    LDXR(0)
    LDXR(1)
    DMAW(0, 0)
    DMAW(1, 1)
    WAITLGKM0();   // publish bsl/bql ds_writes before first barrier

    STEP(0, 6)     // drains x0,x1,w0
    STEP(1, 8)     // drains w1
    STEP(2, 8)
    STEP(3, 8)
    STEP(4, 8)
    STEP(5, 8)
    STEP(6, 6)     // no new issues; drains x6,w6
    STEP(7, 0)

    // ---- epilogue: LDS-transposed full-line nt stores (STEP(7) ended with barrier)
    char* ostage = (char*)wl;       // 32 x 2048B rows = 64 KB
    const int mloc = lane & 15, ocr = (lane >> 4) * 4;
    const char* outb = (char*)out + rbase * 2048 + t * 16;
#pragma unroll
    for (int h = 0; h < 2; h++) {
        if (wm == h) {
#pragma unroll
            for (int ni = 0; ni < 8; ni++) {
                int oc0 = wn * 128 + ni * 16 + ocr;
                float4 s4 = *(const float4*)&bsl[oc0];
                float4 q4 = *(const float4*)&bql[oc0];
#pragma unroll
                for (int mi = 0; mi < 2; mi++) {
                    int row = mi * 16 + mloc;
                    v4f v;
                    v[0] = (float)acc[mi][ni][0] * s4.x + q4.x;
                    v[1] = (float)acc[mi][ni][1] * s4.y + q4.y;
                    v[2] = (float)acc[mi][ni][2] * s4.z + q4.z;
                    v[3] = (float)acc[mi][ni][3] * s4.w + q4.w;
                    int byte = (row * 2048 + oc0 * 4) ^ ((row & 15) << 4);
                    *(v4f*)(ostage + byte) = v;
                }
            }
        }
        WAITLGKM0();
        __builtin_amdgcn_s_barrier();
#pragma unroll
        for (int i = 0; i < 8; i++) {
            int flat = t * 16 + i * 8192;
            int row = flat >> 11;
            v4f v = *(const v4f*)(ostage + (flat ^ ((row & 15) << 4)));
            __builtin_nontemporal_store(v, (v4f*)(outb + h * 65536 + i * 8192));
        }
        if (h == 0) {
            WAITLGKM0();
            __builtin_amdgcn_s_barrier();   // reads done before h=1 overwrites
        }
    }
#undef DMAW
#undef LDXR
#undef COMPUTE
#undef STEP
}

// ---------------- Fallback GEMM (R8 path, used only if ws too small for x8) ----------------
__global__ __launch_bounds__(512, 4) void gemm_fb_kernel(
    const float* __restrict__ x, const char* __restrict__ wq,
    const float* __restrict__ bs, const float* __restrict__ bq,
    const unsigned* __restrict__ amax, float* __restrict__ out) {
    __shared__ char xl[2][BM * 64];
    __shared__ char wl[2][DOUT * 64];
    const int t = threadIdx.x, lane = t & 63, wid = t >> 6;
    const int wm = wid >> 2, wn = wid & 3;
    const long rbase = (long)blockIdx.x * BM;
    const float as = __uint_as_float(*amax) / 127.0f;
    const float inv_as = 1.0f / as;
    const int xrow = t >> 3, xc = t & 7;
    const float4* xg = (const float4*)(x + (rbase + xrow) * DIN) + xc * 2;
    const int xw_off = ((xrow >> 4) * 64 + (xc >> 1) * 16 + (xrow & 15)) * 16 + (xc & 1) * 8;
    const char* wgsrc = wq + ((wid * 64) + (lane & 15)) * DIN + (lane >> 4) * 16;
    float4 xv[2][2];
    v4i acc[2][8] = {};
#define LOADX(n, s) { const float4* p_ = xg + (n) * 16; xv[s][0] = p_[0]; xv[s][1] = p_[1]; }
#define DMAW(n, b) { _Pragma("unroll") for (int jj = 0; jj < 4; jj++) \
    __builtin_amdgcn_global_load_lds( \
        (const __attribute__((address_space(1))) unsigned*)(wgsrc + jj * 16 * DIN + (n) * 64), \
        (__attribute__((address_space(3))) unsigned*)(wl[b] + (wid * 4 + jj) * 1024), 16, 0, 0); }
#define QUANTX(s, b) { \
    int lo_ = q8m(xv[s][0].x, inv_as) | (q8m(xv[s][0].y, inv_as) << 8) | \
              (q8m(xv[s][0].z, inv_as) << 16) | (q8m(xv[s][0].w, inv_as) << 24); \
    int hi_ = q8m(xv[s][1].x, inv_as) | (q8m(xv[s][1].y, inv_as) << 8) | \
              (q8m(xv[s][1].z, inv_as) << 16) | (q8m(xv[s][1].w, inv_as) << 24); \
    *(int2*)&xl[b][xw_off] = make_int2(lo_, hi_); }
#define COMPUTE(p) { \
    v4i xa0 = *(const v4i*)&xl[p][(wm * 2 + 0) * 1024 + lane * 16]; \
    v4i xa1 = *(const v4i*)&xl[p][(wm * 2 + 1) * 1024 + lane * 16]; \
    _Pragma("unroll") for (int ni = 0; ni < 8; ni++) { \
        v4i wb = *(const v4i*)&wl[p][(wn * 8 + ni) * 1024 + lane * 16]; \
        acc[0][ni] = __builtin_amdgcn_mfma_i32_16x16x64_i8(wb, xa0, acc[0][ni], 0, 0, 0); \
        acc[1][ni] = __builtin_amdgcn_mfma_i32_16x16x64_i8(wb, xa1, acc[1][ni], 0, 0, 0); } }
    LOADX(0, 0); DMAW(0, 0); LOADX(1, 1);
    WAITVM(6); QUANTX(0, 0); WAITLGKM0(); __builtin_amdgcn_s_barrier();
#define STEP_MID(KS, PB) \
    DMAW(KS + 1, PB ^ 1); LOADX(KS + 2, (KS) & 1); \
    WAITVM(8); COMPUTE(PB); WAITVM(6); QUANTX((KS + 1) & 1, PB ^ 1); \
    WAITLGKM0(); __builtin_amdgcn_s_barrier();
    STEP_MID(0, 0) STEP_MID(1, 1) STEP_MID(2, 0) STEP_MID(3, 1) STEP_MID(4, 0) STEP_MID(5, 1)
    DMAW(7, 1); WAITVM(6); COMPUTE(0); WAITVM(4); QUANTX(1, 1);
    WAITLGKM0(); __builtin_amdgcn_s_barrier();
    WAITVM(0); COMPUTE(1);
    __builtin_amdgcn_s_barrier();
    char* ostage = (char*)wl;
    const int mloc = lane & 15, ocr = (lane >> 4) * 4;
    const char* outb = (char*)out + rbase * 2048 + t * 16;
#pragma unroll
    for (int h = 0; h < 2; h++) {
        if (wm == h) {
#pragma unroll
            for (int ni = 0; ni < 8; ni++) {
                int oc0 = wn * 128 + ni * 16 + ocr;
                float4 s4 = *(const float4*)(bs + oc0);
                float4 q4 = *(const float4*)(bq + oc0);
#pragma unroll
                for (int mi = 0; mi < 2; mi++) {
                    int row = mi * 16 + mloc;
                    v4f v;
                    v[0] = (float)acc[mi][ni][0] * s4.x + q4.x;
                    v[1] = (float)acc[mi][ni][1] * s4.y + q4.y;
                    v[2] = (float)acc[mi][ni][2] * s4.z + q4.z;
                    v[3] = (float)acc[mi][ni][3] * s4.w + q4.w;
                    int byte = (row * 2048 + oc0 * 4) ^ ((row & 15) << 4);
                    *(v4f*)(ostage + byte) = v;
                }
            }
        }
        WAITLGKM0();
        __builtin_amdgcn_s_barrier();
#pragma unroll
        for (int i = 0; i < 8; i++) {
            int flat = t * 16 + i * 8192;
            int row = flat >> 11;
            v4f v = *(const v4f*)(ostage + (flat ^ ((row & 15) << 4)));
            __builtin_nontemporal_store(v, (v4f*)(outb + h * 65536 + i * 8192));
        }
        if (h == 0) { WAITLGKM0(); __builtin_amdgcn_s_barrier(); }
    }
#undef LOADX
#undef DMAW
#undef QUANTX
#undef COMPUTE
#undef STEP_MID
}

extern "C" void kernel_launch(void* const* d_in, const int* in_sizes, int n_in,
                              void* d_out, int out_size, void* d_ws, size_t ws_size,
                              hipStream_t stream) {
    const float* x    = (const float*)d_in[0];
    const float* w    = (const float*)d_in[1];
    const float* bias = (const float*)d_in[2];
    float* out = (float*)d_out;
    const int M = in_sizes[0] / DIN;   // 65536

    char* ws = (char*)d_ws;
    unsigned* amax = (unsigned*)ws;
    char* wq   = ws + 64;
    float* wsc = (float*)(ws + 64 + (long)DOUT * DIN);
    float* bs  = wsc + DOUT;
    float* bq  = bs + DOUT;
    char* x8   = (char*)(bq + DOUT);
    const size_t need = 64 + (size_t)DOUT * DIN + 3 * DOUT * 4 + (size_t)M * DIN;

    quantw_kernel<<<(DOUT * 64) / 256, 256, 0, stream>>>(w, wq, wsc, amax);
    absmax_kernel<<<2048, 256, 0, stream>>>((const float4*)x, amax, in_sizes[0] / 4);
    if (ws_size >= need) {
        quantx_kernel<<<(M * DIN / 16) / 512, 512, 0, stream>>>(x, amax, x8);
        gemm_kernel<<<M / BM, 512, 0, stream>>>(x8, wq, wsc, bias, amax, out);
    } else {
        quantb_kernel<<<1, DOUT, 0, stream>>>(bias, wsc, amax, bs, bq);
        gemm_fb_kernel<<<M / BM, 512, 0, stream>>>(x, wq, bs, bq, amax, out);
    }
}

// Round 12
// 112.944 us; speedup vs baseline: 1.4252x; 1.0697x over previous
//
#include <hip/hip_runtime.h>

#define DIN 512
#define DOUT 512
#define BM 64

typedef int v4i __attribute__((ext_vector_type(4)));
typedef float v4f __attribute__((ext_vector_type(4)));

#define WAITVM(n) asm volatile("s_waitcnt vmcnt(" #n ")" ::: "memory")
#define WAITLGKM0() asm volatile("s_waitcnt lgkmcnt(0)" ::: "memory")

// exact-divide quantize (weights/bias path, matches ref bit-for-bit)
__device__ __forceinline__ int q8f(float v, float s) {
    int i = (int)rintf(v / s);
    i = i < -128 ? -128 : (i > 127 ? 127 : i);
    return i & 255;
}
// multiply-by-reciprocal quantize (activation path; flip prob ~2^-22)
__device__ __forceinline__ int q8m(float v, float inv) {
    int i = (int)rintf(v * inv);
    i = i < -128 ? -128 : (i > 127 ? 127 : i);
    return i & 255;
}

// ---------------- Kernel 1: global absmax of x ----------------
__global__ void absmax_kernel(const float4* __restrict__ x4, unsigned* __restrict__ amax, int n4) {
    float m = 0.f;
    int stride = gridDim.x * blockDim.x;
    for (int i = blockIdx.x * blockDim.x + threadIdx.x; i < n4; i += stride) {
        float4 v = x4[i];
        m = fmaxf(m, fmaxf(fmaxf(fabsf(v.x), fabsf(v.y)), fmaxf(fabsf(v.z), fabsf(v.w))));
    }
#pragma unroll
    for (int off = 32; off; off >>= 1) m = fmaxf(m, __shfl_xor(m, off));
    __shared__ float sm[4];
    int lane = threadIdx.x & 63, w = threadIdx.x >> 6;
    if (lane == 0) sm[w] = m;
    __syncthreads();
    if (threadIdx.x == 0) {
        m = fmaxf(fmaxf(sm[0], sm[1]), fmaxf(sm[2], sm[3]));
        atomicMax(amax, __float_as_uint(m));  // positive floats: uint compare == float compare
    }
}

// ---------------- Kernel 2: weight quant -> row-major wq AND frag-linear wq8 ----------------
// wq8 byte(og,ks,kq,r,b) = og*8192 + ks*1024 + kq*256 + r*16 + b  ==>  a wave's
// A-frag (og,ks) is CONTIGUOUS 1KB at wq8 + og*8192 + ks*1024 + lane*16
// (identity: kq=lane>>4, r=lane&15 -> kq*256+r*16 == lane*16).
__global__ void quantw_kernel(const float* __restrict__ w,
                              char* __restrict__ wq, char* __restrict__ wq8,
                              float* __restrict__ wsc, unsigned* __restrict__ amax) {
    int gid = blockIdx.x * blockDim.x + threadIdx.x;
    if (gid == 0) *amax = 0u;   // zero-init; absmax launches after quantw on same stream
    int row = gid >> 6, lane = gid & 63;
    const float4* r4 = (const float4*)(w + (long)row * DIN);
    float4 a = r4[lane * 2];
    float4 b = r4[lane * 2 + 1];
    float m = fmaxf(fmaxf(fmaxf(fabsf(a.x), fabsf(a.y)), fabsf(a.z)),
                    fmaxf(fmaxf(fabsf(a.w), fabsf(b.x)),
                          fmaxf(fmaxf(fabsf(b.y), fabsf(b.z)), fabsf(b.w))));
#pragma unroll
    for (int off = 32; off; off >>= 1) m = fmaxf(m, __shfl_xor(m, off));
    float s = m / 127.0f;
    int lo = q8f(a.x, s) | (q8f(a.y, s) << 8) | (q8f(a.z, s) << 16) | (q8f(a.w, s) << 24);
    int hi = q8f(b.x, s) | (q8f(b.y, s) << 8) | (q8f(b.z, s) << 16) | (q8f(b.w, s) << 24);
    ((int2*)(wq + (long)row * DIN))[lane] = make_int2(lo, hi);
    // frag-linear copy: this thread's 8 bytes are k = lane*8 .. +8 of row
    {
        int og = row >> 4, r = row & 15;
        int ks = lane >> 3, kq = (lane >> 1) & 3, bo = (lane & 1) * 8;
        *(int2*)(wq8 + og * 8192 + ks * 1024 + kq * 256 + r * 16 + bo) = make_int2(lo, hi);
    }
    if (lane == 0) wsc[row] = s;
}

// ---------------- Kernel 2b: combined scales + quantized bias (fallback path only) ----------------
__global__ void quantb_kernel(const float* __restrict__ bias, const float* __restrict__ wsc,
                              const unsigned* __restrict__ amax,
                              float* __restrict__ bs, float* __restrict__ bq) {
    int oc = threadIdx.x;
    float as = __uint_as_float(*amax) / 127.0f;
    float s = as * wsc[oc];
    bs[oc] = s;
    bq[oc] = rintf(bias[oc] / s) * s;
}

// ---------------- Kernel 2c: quantize x -> chunk-linear int8 (+ bs/bq fold in block 0) ----------------
// x8 byte(T,ks,c,kq,r) = T*32768 + ks*4096 + c*1024 + kq*256 + r*16 (validated R9/R11 layout).
__global__ __launch_bounds__(512) void quantx_kernel(
    const float* __restrict__ x, const unsigned* __restrict__ amax,
    const float* __restrict__ wsc, const float* __restrict__ bias,
    char* __restrict__ x8, float* __restrict__ bs, float* __restrict__ bq) {
    const float inv_as = 1.0f / (__uint_as_float(*amax) / 127.0f);
    if (blockIdx.x == 0) {   // fold quantb: one oc per thread
        int oc = threadIdx.x;
        float s = (__uint_as_float(*amax) / 127.0f) * wsc[oc];
        bs[oc] = s;
        bq[oc] = rintf(bias[oc] / s) * s;
    }
    const long g = (long)blockIdx.x * 512 + threadIdx.x;
    const long T = g >> 11;
    const int L = (int)(g & 2047);
    const int ks = L >> 8, c = (L >> 6) & 3, kq = (L >> 4) & 3, r = L & 15;
    const float4* src = (const float4*)(x + (T * 64 + c * 16 + r) * DIN + ks * 64 + kq * 16);
    float4 v0 = src[0], v1 = src[1], v2 = src[2], v3 = src[3];
    v4i q;
    q[0] = q8m(v0.x, inv_as) | (q8m(v0.y, inv_as) << 8) | (q8m(v0.z, inv_as) << 16) | (q8m(v0.w, inv_as) << 24);
    q[1] = q8m(v1.x, inv_as) | (q8m(v1.y, inv_as) << 8) | (q8m(v1.z, inv_as) << 16) | (q8m(v1.w, inv_as) << 24);
    q[2] = q8m(v2.x, inv_as) | (q8m(v2.y, inv_as) << 8) | (q8m(v2.z, inv_as) << 16) | (q8m(v2.w, inv_as) << 24);
    q[3] = q8m(v3.x, inv_as) | (q8m(v3.y, inv_as) << 8) | (q8m(v3.z, inv_as) << 16) | (q8m(v3.w, inv_as) << 24);
    *(v4i*)(x8 + g * 16) = q;
}

// ---------------- Kernel 3: barrier-free per-wave int8 GEMM ----------------
// 512 blocks x 256 thr (4 waves). After ONE bsl/bql staging barrier, each wave
// is fully independent: it owns 32 m-rows x 512 oc. xa (32 rows x 512 k int8)
// = 64 VGPR, loaded once from L3-hot x8 (contiguous 1KB/frag). Loop 32
// oc-groups: 8 contiguous wq8 loads (ping-pong, issued one FULL group (~320cy
// MFMA) ahead of use > L2 latency), 16 MFMA in 4 accumulation chains, scale+
// bias VALU, 2 normal stores (L2 write-combines the 64B segments; R1 evidence:
// no amplification). No LDS operands, no barriers, no waitcnt: waves drift
// apart and HBM/L2 see a continuous mixed stream.
__global__ __launch_bounds__(256, 2) void gemm_kernel(
    const char* __restrict__ x8, const char* __restrict__ wq8,
    const float* __restrict__ bs, const float* __restrict__ bq,
    float* __restrict__ out) {
    __shared__ __align__(16) float bsl[512];
    __shared__ __align__(16) float bql[512];
    const int t = threadIdx.x, lane = t & 63, wid = t >> 6;
    bsl[t] = bs[t];
    bsl[t + 256] = bs[t + 256];
    bql[t] = bq[t];
    bql[t + 256] = bq[t + 256];
    __syncthreads();   // the only barrier

    const int gw = blockIdx.x * 4 + wid;                 // global wave id, 0..2047
    const long m0 = (long)gw * 32;
    const char* xt = x8 + (long)(gw >> 1) * 32768 + (gw & 1) * 2048 + lane * 16;
    const char* wg = wq8 + lane * 16;
    const int bo = (lane >> 4) * 4;                      // oc sub-offset
    float* outr = out + (m0 + (lane & 15)) * DOUT + bo;  // mf=0 row base

    v4i xa[2][8];
#pragma unroll
    for (int ks = 0; ks < 8; ks++) {
        xa[0][ks] = *(const v4i*)(xt + ks * 4096);
        xa[1][ks] = *(const v4i*)(xt + ks * 4096 + 1024);
    }
    v4i wfA[8], wfB[8];
#pragma unroll
    for (int ks = 0; ks < 8; ks++) wfA[ks] = *(const v4i*)(wg + ks * 1024);

#define CEPI(WF, OG) { \
    v4i a00, a01, a10, a11; \
    const v4i Z = {0, 0, 0, 0}; \
    a00 = __builtin_amdgcn_mfma_i32_16x16x64_i8(WF[0], xa[0][0], Z, 0, 0, 0); \
    a10 = __builtin_amdgcn_mfma_i32_16x16x64_i8(WF[0], xa[1][0], Z, 0, 0, 0); \
    a01 = __builtin_amdgcn_mfma_i32_16x16x64_i8(WF[1], xa[0][1], Z, 0, 0, 0); \
    a11 = __builtin_amdgcn_mfma_i32_16x16x64_i8(WF[1], xa[1][1], Z, 0, 0, 0); \
    _Pragma("unroll") for (int kp = 2; kp < 8; kp += 2) { \
        a00 = __builtin_amdgcn_mfma_i32_16x16x64_i8(WF[kp], xa[0][kp], a00, 0, 0, 0); \
        a10 = __builtin_amdgcn_mfma_i32_16x16x64_i8(WF[kp], xa[1][kp], a10, 0, 0, 0); \
        a01 = __builtin_amdgcn_mfma_i32_16x16x64_i8(WF[kp + 1], xa[0][kp + 1], a01, 0, 0, 0); \
        a11 = __builtin_amdgcn_mfma_i32_16x16x64_i8(WF[kp + 1], xa[1][kp + 1], a11, 0, 0, 0); } \
    v4i s0 = a00 + a01, s1 = a10 + a11; \
    float4 s4 = *(const float4*)&bsl[(OG) * 16 + bo]; \
    float4 q4 = *(const float4*)&bql[(OG) * 16 + bo]; \
    v4f v0, v1; \
    v0[0] = (float)s0[0] * s4.x + q4.x; v0[1] = (float)s0[1] * s4.y + q4.y; \
    v0[2] = (float)s0[2] * s4.z + q4.z; v0[3] = (float)s0[3] * s4.w + q4.w; \
    v1[0] = (float)s1[0] * s4.x + q4.x; v1[1] = (float)s1[1] * s4.y + q4.y; \
    v1[2] = (float)s1[2] * s4.z + q4.z; v1[3] = (float)s1[3] * s4.w + q4.w; \
    *(v4f*)(outr + (OG) * 16) = v0; \
    *(v4f*)(outr + 16 * DOUT + (OG) * 16) = v1; }

    for (int og = 0; og < 32; og += 2) {
#pragma unroll
        for (int ks = 0; ks < 8; ks++)
            wfB[ks] = *(const v4i*)(wg + (og + 1) * 8192 + ks * 1024);
        CEPI(wfA, og)
        if (og + 2 < 32) {
#pragma unroll
            for (int ks = 0; ks < 8; ks++)
                wfA[ks] = *(const v4i*)(wg + (og + 2) * 8192 + ks * 1024);
        }
        CEPI(wfB, og + 1)
    }
#undef CEPI
}

// ---------------- Fallback GEMM (R8/R11 path, used only if ws too small) ----------------
__global__ __launch_bounds__(512, 4) void gemm_fb_kernel(
    const float* __restrict__ x, const char* __restrict__ wq,
    const float* __restrict__ bs, const float* __restrict__ bq,
    const unsigned* __restrict__ amax, float* __restrict__ out) {
    __shared__ char xl[2][BM * 64];
    __shared__ char wl[2][DOUT * 64];
    const int t = threadIdx.x, lane = t & 63, wid = t >> 6;
    const int wm = wid >> 2, wn = wid & 3;
    const long rbase = (long)blockIdx.x * BM;
    const float as = __uint_as_float(*amax) / 127.0f;
    const float inv_as = 1.0f / as;
    const int xrow = t >> 3, xc = t & 7;
    const float4* xg = (const float4*)(x + (rbase + xrow) * DIN) + xc * 2;
    const int xw_off = ((xrow >> 4) * 64 + (xc >> 1) * 16 + (xrow & 15)) * 16 + (xc & 1) * 8;
    const char* wgsrc = wq + ((wid * 64) + (lane & 15)) * DIN + (lane >> 4) * 16;
    float4 xv[2][2];
    v4i acc[2][8] = {};
#define LOADX(n, s) { const float4* p_ = xg + (n) * 16; xv[s][0] = p_[0]; xv[s][1] = p_[1]; }
#define DMAW(n, b) { _Pragma("unroll") for (int jj = 0; jj < 4; jj++) \
    __builtin_amdgcn_global_load_lds( \
        (const __attribute__((address_space(1))) unsigned*)(wgsrc + jj * 16 * DIN + (n) * 64), \
        (__attribute__((address_space(3))) unsigned*)(wl[b] + (wid * 4 + jj) * 1024), 16, 0, 0); }
#define QUANTX(s, b) { \
    int lo_ = q8m(xv[s][0].x, inv_as) | (q8m(xv[s][0].y, inv_as) << 8) | \
              (q8m(xv[s][0].z, inv_as) << 16) | (q8m(xv[s][0].w, inv_as) << 24); \
    int hi_ = q8m(xv[s][1].x, inv_as) | (q8m(xv[s][1].y, inv_as) << 8) | \
              (q8m(xv[s][1].z, inv_as) << 16) | (q8m(xv[s][1].w, inv_as) << 24); \
    *(int2*)&xl[b][xw_off] = make_int2(lo_, hi_); }
#define COMPUTE(p) { \
    v4i xa0 = *(const v4i*)&xl[p][(wm * 2 + 0) * 1024 + lane * 16]; \
    v4i xa1 = *(const v4i*)&xl[p][(wm * 2 + 1) * 1024 + lane * 16]; \
    _Pragma("unroll") for (int ni = 0; ni < 8; ni++) { \
        v4i wb = *(const v4i*)&wl[p][(wn * 8 + ni) * 1024 + lane * 16]; \
        acc[0][ni] = __builtin_amdgcn_mfma_i32_16x16x64_i8(wb, xa0, acc[0][ni], 0, 0, 0); \
        acc[1][ni] = __builtin_amdgcn_mfma_i32_16x16x64_i8(wb, xa1, acc[1][ni], 0, 0, 0); } }
    LOADX(0, 0); DMAW(0, 0); LOADX(1, 1);
    WAITVM(6); QUANTX(0, 0); WAITLGKM0(); __builtin_amdgcn_s_barrier();
#define STEP_MID(KS, PB) \
    DMAW(KS + 1, PB ^ 1); LOADX(KS + 2, (KS) & 1); \
    WAITVM(8); COMPUTE(PB); WAITVM(6); QUANTX((KS + 1) & 1, PB ^ 1); \
    WAITLGKM0(); __builtin_amdgcn_s_barrier();
    STEP_MID(0, 0) STEP_MID(1, 1) STEP_MID(2, 0) STEP_MID(3, 1) STEP_MID(4, 0) STEP_MID(5, 1)
    DMAW(7, 1); WAITVM(6); COMPUTE(0); WAITVM(4); QUANTX(1, 1);
    WAITLGKM0(); __builtin_amdgcn_s_barrier();
    WAITVM(0); COMPUTE(1);
    __builtin_amdgcn_s_barrier();
    char* ostage = (char*)wl;
    const int mloc = lane & 15, ocr = (lane >> 4) * 4;
    const char* outb = (char*)out + rbase * 2048 + t * 16;
#pragma unroll
    for (int h = 0; h < 2; h++) {
        if (wm == h) {
#pragma unroll
            for (int ni = 0; ni < 8; ni++) {
                int oc0 = wn * 128 + ni * 16 + ocr;
                float4 s4 = *(const float4*)(bs + oc0);
                float4 q4 = *(const float4*)(bq + oc0);
#pragma unroll
                for (int mi = 0; mi < 2; mi++) {
                    int row = mi * 16 + mloc;
                    v4f v;
                    v[0] = (float)acc[mi][ni][0] * s4.x + q4.x;
                    v[1] = (float)acc[mi][ni][1] * s4.y + q4.y;
                    v[2] = (float)acc[mi][ni][2] * s4.z + q4.z;
                    v[3] = (float)acc[mi][ni][3] * s4.w + q4.w;
                    int byte = (row * 2048 + oc0 * 4) ^ ((row & 15) << 4);
                    *(v4f*)(ostage + byte) = v;
                }
            }
        }
        WAITLGKM0();
        __builtin_amdgcn_s_barrier();
#pragma unroll
        for (int i = 0; i < 8; i++) {
            int flat = t * 16 + i * 8192;
            int row = flat >> 11;
            v4f v = *(const v4f*)(ostage + (flat ^ ((row & 15) << 4)));
            __builtin_nontemporal_store(v, (v4f*)(outb + h * 65536 + i * 8192));
        }
        if (h == 0) { WAITLGKM0(); __builtin_amdgcn_s_barrier(); }
    }
#undef LOADX
#undef DMAW
#undef QUANTX
#undef COMPUTE
#undef STEP_MID
}

extern "C" void kernel_launch(void* const* d_in, const int* in_sizes, int n_in,
                              void* d_out, int out_size, void* d_ws, size_t ws_size,
                              hipStream_t stream) {
    const float* x    = (const float*)d_in[0];
    const float* w    = (const float*)d_in[1];
    const float* bias = (const float*)d_in[2];
    float* out = (float*)d_out;
    const int M = in_sizes[0] / DIN;   // 65536

    char* ws = (char*)d_ws;
    unsigned* amax = (unsigned*)ws;
    char* wq   = ws + 64;
    char* wq8  = wq + (long)DOUT * DIN;
    float* wsc = (float*)(wq8 + (long)DOUT * DIN);
    float* bs  = wsc + DOUT;
    float* bq  = bs + DOUT;
    char* x8   = (char*)(bq + DOUT);
    const size_t need = 64 + 2 * (size_t)DOUT * DIN + 3 * DOUT * 4 + (size_t)M * DIN;

    quantw_kernel<<<(DOUT * 64) / 256, 256, 0, stream>>>(w, wq, wq8, wsc, amax);
    absmax_kernel<<<2048, 256, 0, stream>>>((const float4*)x, amax, in_sizes[0] / 4);
    if (ws_size >= need) {
        quantx_kernel<<<(M * DIN / 16) / 512, 512, 0, stream>>>(x, amax, wsc, bias, x8, bs, bq);
        gemm_kernel<<<M / 128, 256, 0, stream>>>(x8, wq8, bs, bq, out);
    } else {
        quantb_kernel<<<1, DOUT, 0, stream>>>(bias, wsc, amax, bs, bq);
        gemm_fb_kernel<<<M / BM, 512, 0, stream>>>(x, wq, bs, bq, amax, out);
    }
}

// Round 13
// 101.801 us; speedup vs baseline: 1.5812x; 1.1095x over previous
//
#include <hip/hip_runtime.h>

#define DIN 512
#define DOUT 512

typedef int v4i __attribute__((ext_vector_type(4)));
typedef float v4f __attribute__((ext_vector_type(4)));

// exact-divide quantize (weights/bias path, matches ref bit-for-bit)
__device__ __forceinline__ int q8f(float v, float s) {
    int i = (int)rintf(v / s);
    i = i < -128 ? -128 : (i > 127 ? 127 : i);
    return i & 255;
}
// multiply-by-reciprocal quantize (activation path; flip prob ~2^-22, contribution ~0.005 << 0.0525)
__device__ __forceinline__ int q8m(float v, float inv) {
    int i = (int)rintf(v * inv);
    i = i < -128 ? -128 : (i > 127 ? 127 : i);
    return i & 255;
}

// ---------------- Kernel 1: global absmax of x ----------------
__global__ void absmax_kernel(const float4* __restrict__ x4, unsigned* __restrict__ amax, int n4) {
    float m = 0.f;
    int stride = gridDim.x * blockDim.x;
    for (int i = blockIdx.x * blockDim.x + threadIdx.x; i < n4; i += stride) {
        float4 v = x4[i];
        m = fmaxf(m, fmaxf(fmaxf(fabsf(v.x), fabsf(v.y)), fmaxf(fabsf(v.z), fabsf(v.w))));
    }
#pragma unroll
    for (int off = 32; off; off >>= 1) m = fmaxf(m, __shfl_xor(m, off));
    __shared__ float sm[4];
    int lane = threadIdx.x & 63, w = threadIdx.x >> 6;
    if (lane == 0) sm[w] = m;
    __syncthreads();
    if (threadIdx.x == 0) {
        m = fmaxf(fmaxf(sm[0], sm[1]), fmaxf(sm[2], sm[3]));
        atomicMax(amax, __float_as_uint(m));  // positive floats: uint compare == float compare
    }
}

// ---------------- Kernel 2: weight quant -> frag-linear wq8 (+ amax zero-init) ----------------
// wq8 byte(og,ks,kq,r,b) = og*8192 + ks*1024 + kq*256 + r*16 + b ==> a wave's
// A-frag (og,ks) is CONTIGUOUS 1KB at wq8 + og*8192 + ks*1024 + lane*16
// (identity: this thread's 8 bytes are k=lane*8..+8 of row; ks=lane>>3,
// kq=(lane>>1)&3, byte=(lane&1)*8). Validated in R12.
__global__ void quantw_kernel(const float* __restrict__ w, char* __restrict__ wq8,
                              float* __restrict__ wsc, unsigned* __restrict__ amax) {
    int gid = blockIdx.x * blockDim.x + threadIdx.x;
    if (gid == 0) *amax = 0u;   // zero-init; absmax launches after quantw on same stream
    int row = gid >> 6, lane = gid & 63;
    const float4* r4 = (const float4*)(w + (long)row * DIN);
    float4 a = r4[lane * 2];
    float4 b = r4[lane * 2 + 1];
    float m = fmaxf(fmaxf(fmaxf(fabsf(a.x), fabsf(a.y)), fabsf(a.z)),
                    fmaxf(fmaxf(fabsf(a.w), fabsf(b.x)),
                          fmaxf(fmaxf(fabsf(b.y), fabsf(b.z)), fabsf(b.w))));
#pragma unroll
    for (int off = 32; off; off >>= 1) m = fmaxf(m, __shfl_xor(m, off));
    float s = m / 127.0f;
    int lo = q8f(a.x, s) | (q8f(a.y, s) << 8) | (q8f(a.z, s) << 16) | (q8f(a.w, s) << 24);
    int hi = q8f(b.x, s) | (q8f(b.y, s) << 8) | (q8f(b.z, s) << 16) | (q8f(b.w, s) << 24);
    {
        int og = row >> 4, r = row & 15;
        int ks = lane >> 3, kq = (lane >> 1) & 3, bo = (lane & 1) * 8;
        *(int2*)(wq8 + og * 8192 + ks * 1024 + kq * 256 + r * 16 + bo) = make_int2(lo, hi);
    }
    if (lane == 0) wsc[row] = s;
}

// ---------------- Kernel 3: barrier-free per-wave GEMM with in-register x-quant ----------------
// 512 blocks x 256 thr (4 waves). Prologue: fold quantb (bsl/bql in LDS), one
// __syncthreads. Then each wave fully independent, owning 32 m-rows x 512 oc.
//
// x-phase: the B-frag a lane needs is 16 consecutive k-bytes of ONE row
// (row m0+mi*16+(lane&15), k=ks*64+(lane>>4)*16..+16) == 16 consecutive fp32
// == one 64B contiguous read. Lane loads 4xfloat4 (L3-hot after absmax),
// quantizes in REGISTERS -> xa[mi][ks] directly. No LDS, no cross-lane moves,
// no quantx pass. 16 batches, depth-3 pipeline (12 float4 in flight).
//
// og-loop (R12-validated): 8 contiguous 1KB wq8 loads per og (L2-resident,
// ping-pong one full group ahead), 16 MFMA in 4 chains, scale+bias, 2 normal
// v4f stores (L2 write-combines; R1 evidence: no amplification).
__global__ __launch_bounds__(256, 2) void gemm_kernel(
    const float* __restrict__ x, const char* __restrict__ wq8,
    const float* __restrict__ wsc, const float* __restrict__ bias,
    const unsigned* __restrict__ amax, float* __restrict__ out) {
    __shared__ __align__(16) float bsl[512];
    __shared__ __align__(16) float bql[512];
    const int t = threadIdx.x, lane = t & 63, wid = t >> 6;
    const float as = __uint_as_float(*amax) / 127.0f;
    const float inv_as = 1.0f / as;

    // fold quantb: two oc per thread
    {
        float s0 = as * wsc[t];
        bsl[t] = s0;
        bql[t] = rintf(bias[t] / s0) * s0;
        float s1 = as * wsc[t + 256];
        bsl[t + 256] = s1;
        bql[t + 256] = rintf(bias[t + 256] / s1) * s1;
    }
    __syncthreads();   // the only barrier

    const int gw = blockIdx.x * 4 + wid;                 // global wave id, 0..2047
    const long m0 = (long)gw * 32;
    const float* xb = x + (m0 + (lane & 15)) * DIN + (lane >> 4) * 16;
    const char* wg = wq8 + lane * 16;
    const int bo = (lane >> 4) * 4;                      // oc sub-offset
    float* outr = out + (m0 + (lane & 15)) * DOUT + bo;  // mi=0 row base

    // ---- pre-issue first w-group (L2) so CEPI(0) doesn't stall
    v4i wfA[8], wfB[8];
#pragma unroll
    for (int ks = 0; ks < 8; ks++) wfA[ks] = *(const v4i*)(wg + ks * 1024);

    // ---- x-phase: 16 batches (mi,ks), 4 float4 each, quantize in-register
    v4i xa[2][8];
    float4 xv[3][4];
#define LOADB(B, S) { const float4* p_ = (const float4*)(xb + ((B) >> 3) * (16 * DIN) + ((B) & 7) * 64); \
        xv[S][0] = p_[0]; xv[S][1] = p_[1]; xv[S][2] = p_[2]; xv[S][3] = p_[3]; }
#define PK(v) (q8m((v).x, inv_as) | (q8m((v).y, inv_as) << 8) | \
               (q8m((v).z, inv_as) << 16) | (q8m((v).w, inv_as) << 24))
#define QUANTB(B, S) { v4i q_; \
        q_[0] = PK(xv[S][0]); q_[1] = PK(xv[S][1]); q_[2] = PK(xv[S][2]); q_[3] = PK(xv[S][3]); \
        xa[(B) >> 3][(B) & 7] = q_; }

    LOADB(0, 0)
    LOADB(1, 1)
#pragma unroll
    for (int b = 0; b < 16; b++) {
        if (b + 2 < 16) LOADB(b + 2, (b + 2) % 3)
        QUANTB(b, b % 3)
    }

    // ---- og-loop: stream wq8 from L2, 16 MFMA per og, scale+bias, store
#define CEPI(WF, OG) { \
    v4i a00, a01, a10, a11; \
    const v4i Z = {0, 0, 0, 0}; \
    a00 = __builtin_amdgcn_mfma_i32_16x16x64_i8(WF[0], xa[0][0], Z, 0, 0, 0); \
    a10 = __builtin_amdgcn_mfma_i32_16x16x64_i8(WF[0], xa[1][0], Z, 0, 0, 0); \
    a01 = __builtin_amdgcn_mfma_i32_16x16x64_i8(WF[1], xa[0][1], Z, 0, 0, 0); \
    a11 = __builtin_amdgcn_mfma_i32_16x16x64_i8(WF[1], xa[1][1], Z, 0, 0, 0); \
    _Pragma("unroll") for (int kp = 2; kp < 8; kp += 2) { \
        a00 = __builtin_amdgcn_mfma_i32_16x16x64_i8(WF[kp], xa[0][kp], a00, 0, 0, 0); \
        a10 = __builtin_amdgcn_mfma_i32_16x16x64_i8(WF[kp], xa[1][kp], a10, 0, 0, 0); \
        a01 = __builtin_amdgcn_mfma_i32_16x16x64_i8(WF[kp + 1], xa[0][kp + 1], a01, 0, 0, 0); \
        a11 = __builtin_amdgcn_mfma_i32_16x16x64_i8(WF[kp + 1], xa[1][kp + 1], a11, 0, 0, 0); } \
    v4i s0 = a00 + a01, s1 = a10 + a11; \
    float4 s4 = *(const float4*)&bsl[(OG) * 16 + bo]; \
    float4 q4 = *(const float4*)&bql[(OG) * 16 + bo]; \
    v4f v0, v1; \
    v0[0] = (float)s0[0] * s4.x + q4.x; v0[1] = (float)s0[1] * s4.y + q4.y; \
    v0[2] = (float)s0[2] * s4.z + q4.z; v0[3] = (float)s0[3] * s4.w + q4.w; \
    v1[0] = (float)s1[0] * s4.x + q4.x; v1[1] = (float)s1[1] * s4.y + q4.y; \
    v1[2] = (float)s1[2] * s4.z + q4.z; v1[3] = (float)s1[3] * s4.w + q4.w; \
    *(v4f*)(outr + (OG) * 16) = v0; \
    *(v4f*)(outr + 16 * DOUT + (OG) * 16) = v1; }

    for (int og = 0; og < 32; og += 2) {
#pragma unroll
        for (int ks = 0; ks < 8; ks++)
            wfB[ks] = *(const v4i*)(wg + (og + 1) * 8192 + ks * 1024);
        CEPI(wfA, og)
        if (og + 2 < 32) {
#pragma unroll
            for (int ks = 0; ks < 8; ks++)
                wfA[ks] = *(const v4i*)(wg + (og + 2) * 8192 + ks * 1024);
        }
        CEPI(wfB, og + 1)
    }
#undef LOADB
#undef PK
#undef QUANTB
#undef CEPI
}

extern "C" void kernel_launch(void* const* d_in, const int* in_sizes, int n_in,
                              void* d_out, int out_size, void* d_ws, size_t ws_size,
                              hipStream_t stream) {
    const float* x    = (const float*)d_in[0];
    const float* w    = (const float*)d_in[1];
    const float* bias = (const float*)d_in[2];
    float* out = (float*)d_out;
    const int M = in_sizes[0] / DIN;   // 65536

    char* ws = (char*)d_ws;
    unsigned* amax = (unsigned*)ws;
    char* wq8  = ws + 64;
    float* wsc = (float*)(wq8 + (long)DOUT * DIN);

    quantw_kernel<<<(DOUT * 64) / 256, 256, 0, stream>>>(w, wq8, wsc, amax);
    absmax_kernel<<<2048, 256, 0, stream>>>((const float4*)x, amax, in_sizes[0] / 4);
    gemm_kernel<<<M / 128, 256, 0, stream>>>(x, wq8, wsc, bias, amax, out);
}